// Round 4
// baseline (121.750 us; speedup 1.0000x reference)
//
#include <hip/hip_runtime.h>

// cvmm: out[m] = x[m] @ w[sel[m]]
// x: [M,64] f32, sel: [M] i32, w: [8,64,64] f32, out: [M,64] f32
//
// R9: steady-state streaming. R5-R8 all put the grid's reads in one lockstep
// burst (one-shot blocks: every wave issues all loads at t=0, queue drains
// ~10-16us while everyone waits, then a pure-write burst) -> avg 2.4 TB/s
// while each burst runs at 6.3. Also: R5/R8's asm "+v" pin of W-fragments sat
// AFTER the x loads -> forced vmcnt(0) drain of the whole prologue.
// This version:
//  - 512 persistent blocks (2/CU) x 4 generations x 128 tokens. Double-
//    buffered x tile; depth-2 register prefetch (gen g issues gen g+2's
//    loads), sched_barrier-pinned so the compiler can't sink it.
//  - stream-out of gen g-1 placed INSIDE gen g between stage and compute:
//    2 lgkmcnt-only barriers per gen; reads+writes interleave continuously.
//  - W pin loads issued FIRST and pinned before any x load is in the queue.
//  - compute core verbatim from R8 (sort, operand-swapped MFMA, obuf with
//    272B rows, 1KB-contiguous full-line out stores).
// LDS 68KB -> 2 blocks/CU; VGPR ~150 -> fits 2 waves/SIMD.

typedef __bf16 bf16x8 __attribute__((ext_vector_type(8)));
typedef __bf16 bf16x4 __attribute__((ext_vector_type(4)));
typedef float  floatx4 __attribute__((ext_vector_type(4)));

#define CT    128   // tokens per generation per block
#define NBLK  512   // persistent blocks
#define ITERS 4     // generations: NBLK*ITERS*CT = 262144

// ---- prep: pack w into A-operand fragment layout --------------------------
// entry id = ((e*2 + t)*4 + nt)*64 + lane ; content (q=lane>>4, l16=lane&15):
//   f[j] = w[e][t*32 + q*8 + j][nt*16 + l16]   (j = 0..7)
__global__ __launch_bounds__(256) void wpack_kernel(
    const float* __restrict__ w, bf16x8* __restrict__ wp)
{
    const int id   = blockIdx.x * 256 + threadIdx.x;   // 0..4095
    const int lane = id & 63;
    const int nt   = (id >> 6) & 3;
    const int t    = (id >> 8) & 1;
    const int e    = id >> 9;
    const int q = lane >> 4, l16 = lane & 15;
    const float* src = w + (((e * 64) + t * 32 + q * 8) * 64) + nt * 16 + l16;
    bf16x8 f;
#pragma unroll
    for (int j = 0; j < 8; ++j) f[j] = (__bf16)src[j * 64];
    wp[id] = f;
}

// Raw barrier: drain LDS ops only; global prefetch stays in flight.
#define BAR() do {                                         \
    __builtin_amdgcn_sched_barrier(0);                     \
    asm volatile("s_waitcnt lgkmcnt(0)" ::: "memory");     \
    __builtin_amdgcn_s_barrier();                          \
    __builtin_amdgcn_sched_barrier(0);                     \
} while (0)

// ---- main -----------------------------------------------------------------
__global__ __launch_bounds__(256, 2) void cvmm_kernel(
    const float* __restrict__ x,
    const int* __restrict__ sel,
    const bf16x8* __restrict__ wp,
    float* __restrict__ out)
{
    // x tile: 128 slot-rows x 128B bf16; granules XOR-swizzled by row.
    __shared__ __align__(16) unsigned char xls[2][CT * 128];   // 32 KB
    // out staging: 128 token-rows x 272B (16 granules + 1 pad granule).
    __shared__ __align__(16) unsigned char obuf[CT * 272];     // 34 KB
    __shared__ unsigned int sortLds[2][CT];   // slot -> token | expert<<8
    __shared__ unsigned int invLds[2][CT];    // token -> slot

    const int T    = threadIdx.x;
    const int lane = T & 63;
    const int wv   = T >> 6;     // 0..3 -> n-tile
    const int q    = lane >> 4;  // 0..3
    const int l16  = lane & 15;

    const int wrow = T >> 4;         // staging row-within-16
    const int gl   = (T & 15) >> 1;  // staging granule
    const int hB   = (T & 1) * 8;    // 8-B half within granule
    const int roffA = ((q)     ^ (l16 & 7)) << 4;
    const int roffB = ((q + 4) ^ (l16 & 7)) << 4;

    bf16x8 zf;
#pragma unroll
    for (int j = 0; j < 8; ++j) zf[j] = (__bf16)0.0f;

    // ---- W fragments FIRST: issue, pin (forces wait on these 16 L2-hot
    // loads only — nothing else is in the vm queue yet).
    const bf16x8* wpw = wp + wv * 64 + lane;
    floatx4 bfp[8][2];
#pragma unroll
    for (int e = 0; e < 8; ++e)
#pragma unroll
        for (int t = 0; t < 2; ++t)
            bfp[e][t] = __builtin_bit_cast(floatx4, wpw[e * 512 + t * 256]);
#pragma unroll
    for (int e = 0; e < 8; ++e)
        asm volatile("" : "+v"(bfp[e][0]), "+v"(bfp[e][1]));

    // ---- prologue prefetch: gen 0 and gen 1 (sel first, then x)
    int sA0 = 0, sA1 = 0, sB0 = 0, sB1 = 0;
    floatx4 RA[8], RB[8];
    {
        const long i0 = (long)blockIdx.x;            // gen 0 item
        const long i1 = (long)NBLK + blockIdx.x;     // gen 1 item
        if (wv == 0) {
            sA0 = sel[i0 * CT + lane]; sA1 = sel[i0 * CT + 64 + lane];
            sB0 = sel[i1 * CT + lane]; sB1 = sel[i1 * CT + 64 + lane];
        }
        const float* xc0 = x + i0 * CT * 64;
        const float* xc1 = x + i1 * CT * 64;
        __builtin_amdgcn_sched_barrier(0);
#pragma unroll
        for (int i = 0; i < 8; ++i)
            RA[i] = *(const floatx4*)(xc0 + i * 1024 + 4 * T);
#pragma unroll
        for (int i = 0; i < 8; ++i)
            RB[i] = *(const floatx4*)(xc1 + i * 1024 + 4 * T);
        __builtin_amdgcn_sched_barrier(0);
    }

    // Stream-out of generation pg's obuf contents (1KB-contiguous stores).
#define STREAM(pg)                                                           \
    {                                                                        \
        float* og = out + ((long)(pg) * NBLK + blockIdx.x) * CT * 64;        \
        _Pragma("unroll")                                                    \
        for (int i = 0; i < 8; ++i) {                                        \
            const int G = i * 256 + T;                                       \
            const floatx4 v =                                                \
                *(const floatx4*)(obuf + (G >> 4) * 272 + (G & 15) * 16);    \
            *(floatx4*)(og + (long)G * 4) = v;                               \
        }                                                                    \
    }

#define BODY(g, RX, sX0, sX1)                                                \
    {                                                                        \
        const int  buf  = (g) & 1;                                           \
        const long item = (long)(g) * NBLK + blockIdx.x;                     \
        /* sort current gen (wave 0, in-register, stable) */                 \
        if (wv == 0) {                                                       \
            const unsigned long long lt = (1ull << lane) - 1;                \
            int slot0 = 0, slot1 = 0, pref = 0;                              \
            _Pragma("unroll")                                                \
            for (int e = 0; e < 8; ++e) {                                    \
                unsigned long long m0 = __ballot(sX0 == e);                  \
                unsigned long long m1 = __ballot(sX1 == e);                  \
                if (sX0 == e) slot0 = pref + __popcll(m0 & lt);              \
                if (sX1 == e) slot1 = pref + __popcll(m0) + __popcll(m1 & lt); \
                pref += __popcll(m0) + __popcll(m1);                         \
            }                                                                \
            invLds[buf][lane]      = (unsigned)slot0;                        \
            invLds[buf][64 + lane] = (unsigned)slot1;                        \
            sortLds[buf][slot0] = (unsigned)lane        | ((unsigned)sX0 << 8); \
            sortLds[buf][slot1] = (unsigned)(64 + lane) | ((unsigned)sX1 << 8); \
        }                                                                    \
        BAR();                                                               \
        /* stage RX -> xls[buf] (token row -> sorted slot row, swizzled) */  \
        {                                                                    \
            unsigned char* lb = xls[buf];                                    \
            _Pragma("unroll")                                                \
            for (int i = 0; i < 8; ++i) {                                    \
                const int slot = (int)invLds[buf][i * 16 + wrow];            \
                bf16x4 v;                                                    \
                v[0] = (__bf16)RX[i][0]; v[1] = (__bf16)RX[i][1];            \
                v[2] = (__bf16)RX[i][2]; v[3] = (__bf16)RX[i][3];            \
                *(bf16x4*)(lb + slot * 128 + ((gl ^ (slot & 7)) << 4) + hB) = v; \
            }                                                                \
        }                                                                    \
        /* prefetch gen g+2 into the regs just freed (pinned cluster) */     \
        if ((g) + 2 < ITERS) {                                               \
            const long ni = (long)((g) + 2) * NBLK + blockIdx.x;             \
            if (wv == 0) {                                                   \
                sX0 = sel[ni * CT + lane];                                   \
                sX1 = sel[ni * CT + 64 + lane];                              \
            }                                                                \
            const float* xc = x + ni * CT * 64;                              \
            __builtin_amdgcn_sched_barrier(0);                               \
            _Pragma("unroll")                                                \
            for (int i = 0; i < 8; ++i)                                      \
                RX[i] = *(const floatx4*)(xc + i * 1024 + 4 * T);            \
            __builtin_amdgcn_sched_barrier(0);                               \
        }                                                                    \
        /* stream out PREVIOUS gen while this gen's reads are in flight */   \
        if ((g) > 0) STREAM((g) - 1);                                        \
        BAR();                                                               \
        /* compute 8 m-tiles -> obuf (R8 core) */                            \
        {                                                                    \
            const unsigned char* lb = xls[buf];                              \
            _Pragma("unroll")                                                \
            for (int i = 0; i < 8; ++i) {                                    \
                const unsigned u = sortLds[buf][i * 16 + l16];               \
                const int tokL = (int)(u & 255u);                            \
                const int el   = (int)(u >> 8);                              \
                const int rb   = (i * 16 + l16) * 128;                       \
                const bf16x8 af0 = *(const bf16x8*)(lb + rb + roffA);        \
                const bf16x8 af1 = *(const bf16x8*)(lb + rb + roffB);        \
                const int elo = __builtin_amdgcn_readfirstlane(el);          \
                const int ehi = __builtin_amdgcn_readlane(el, 15);           \
                floatx4 acc = {0.0f, 0.0f, 0.0f, 0.0f};                      \
                _Pragma("unroll")                                            \
                for (int e = 0; e < 8; ++e) {                                \
                    if (e >= elo && e <= ehi) {                              \
                        const bool ok = (el == e);                           \
                        acc = __builtin_amdgcn_mfma_f32_16x16x32_bf16(       \
                                  __builtin_bit_cast(bf16x8, bfp[e][0]),     \
                                  ok ? af0 : zf, acc, 0, 0, 0);              \
                        acc = __builtin_amdgcn_mfma_f32_16x16x32_bf16(       \
                                  __builtin_bit_cast(bf16x8, bfp[e][1]),     \
                                  ok ? af1 : zf, acc, 0, 0, 0);              \
                    }                                                        \
                }                                                            \
                *(floatx4*)(obuf + tokL * 272 + (wv * 4 + q) * 16) = acc;    \
            }                                                                \
        }                                                                    \
    }

    BODY(0, RA, sA0, sA1)
    BODY(1, RB, sB0, sB1)
    BODY(2, RA, sA0, sA1)
    BODY(3, RB, sB0, sB1)
#undef BODY

    // epilogue: last generation's output
    BAR();
    STREAM(ITERS - 1);
#undef STREAM
}

extern "C" void kernel_launch(void* const* d_in, const int* in_sizes, int n_in,
                              void* d_out, int out_size, void* d_ws, size_t ws_size,
                              hipStream_t stream) {
    const float* x   = (const float*)d_in[0];
    const int*   sel = (const int*)d_in[1];
    const float* w   = (const float*)d_in[2];
    float*       out = (float*)d_out;

    bf16x8* wp = (bf16x8*)d_ws;                     // 64 KB packed fragments

    wpack_kernel<<<16, 256, 0, stream>>>(w, wp);
    cvmm_kernel<<<NBLK, 256, 0, stream>>>(x, sel, wp, out);  // 512*4*128 = M
}